// Round 1
// baseline (191.601 us; speedup 1.0000x reference)
//
#include <hip/hip_runtime.h>
#include <math.h>

#define CC   256   // clusters (fixed by problem)
#define TILE 256   // points per block

// float-offsets within workspace
#define OFF_P     0        // 256 x float4: (mu_x, mu_y, mu_z, alpha)
#define OFF_Q     1024     // 256 x float4: (mu_new_x, mu_new_y, mu_new_z, 0)
#define OFF_M2    2048     // 256: ||mu_c||^2
#define OFF_S     2304     // 256: S_c = sum_n gamma
#define OFF_AX    2560     // 256
#define OFF_AY    2816     // 256
#define OFF_AZ    3072     // 256
#define OFF_CONST 3328     // [0]=twok [1]=lgn [2]=sumGD2 [3]=sumGL2 [4]=sumY2 [5]=sumSM2 [6]=sumSlpi [7]=inv2sn2
#define OFF_T2    3344     // N floats: per-point log2-normalizer

__global__ __launch_bounds__(256) void gmm_prep(const float* __restrict__ mu,
                                                const float* __restrict__ w,
                                                const float* __restrict__ sigma,
                                                float* __restrict__ ws)
{
    __shared__ float redA[4], redB[4];
    const int c = threadIdx.x;
    const int lane = c & 63, wid = c >> 6;
    float wc = w[c];
    // Zw = logsumexp(w) over 256 entries
    float m = wc;
    #pragma unroll
    for (int off = 32; off > 0; off >>= 1) m = fmaxf(m, __shfl_xor(m, off));
    if (lane == 0) redA[wid] = m;
    __syncthreads();
    m = fmaxf(fmaxf(redA[0], redA[1]), fmaxf(redA[2], redA[3]));
    float e = expf(wc - m);
    #pragma unroll
    for (int off = 32; off > 0; off >>= 1) e += __shfl_xor(e, off);
    if (lane == 0) redB[wid] = e;
    __syncthreads();
    float Zw = m + logf(redB[0] + redB[1] + redB[2] + redB[3]);

    const float L = 1.4426950408889634f;   // log2(e)
    float sig = sigma[0];
    float lgn = 3.0f * (logf(sig) + 0.91893853320467274f);  // d*(log sig + 0.5 log 2pi)
    float k = L / (2.0f * sig * sig);
    float mx = mu[3*c], my = mu[3*c+1], mz = mu[3*c+2];
    float m2 = mx*mx + my*my + mz*mz;
    float alpha = (wc - Zw - lgn) * L - k * m2;
    ((float4*)(ws + OFF_P))[c] = make_float4(mx, my, mz, alpha);
    ws[OFF_M2 + c] = m2;
    if (c == 0) { ws[OFF_CONST + 0] = 2.0f * k; ws[OFF_CONST + 1] = lgn; }
}

__global__ __launch_bounds__(256) void gmm_pass1(const float* __restrict__ X,
                                                 float* __restrict__ ws, int N)
{
    __shared__ float4 P[CC];     // (mu, alpha)
    __shared__ float4 XT[TILE];  // (x, y, z, x^2)
    __shared__ float  T2s[TILE];
    __shared__ float  redA[4], redB[4];

    const int tid = threadIdx.x;
    const int n0  = blockIdx.x * TILE;
    const int NT  = min(TILE, N - n0);
    const float twok = ws[OFF_CONST + 0];

    P[tid] = ((const float4*)(ws + OFF_P))[tid];
    if (tid < NT) {
        float x = X[3*(n0+tid)+0], y = X[3*(n0+tid)+1], z = X[3*(n0+tid)+2];
        XT[tid] = make_float4(x, y, z, x*x + y*y + z*z);
    }
    __syncthreads();

    // phase A: one thread per point, LSE over clusters
    if (tid < NT) {
        float4 xt = XT[tid];
        float m = -3.0e38f;
        #pragma unroll 8
        for (int c = 0; c < CC; ++c) {
            float4 p = P[c];
            float dot = fmaf(xt.x, p.x, fmaf(xt.y, p.y, xt.z * p.z));
            float u = fmaf(twok, dot, p.w);
            m = fmaxf(m, u);
        }
        float s = 0.0f;
        #pragma unroll 8
        for (int c = 0; c < CC; ++c) {
            float4 p = P[c];
            float dot = fmaf(xt.x, p.x, fmaf(xt.y, p.y, xt.z * p.z));
            float u = fmaf(twok, dot, p.w);
            s += exp2f(u - m);
        }
        float T2 = m + log2f(s);
        T2s[tid] = T2;
        ws[OFF_T2 + n0 + tid] = T2;
    }
    __syncthreads();

    // phase B: one thread per cluster, register accumulation over the tile
    float4 p = P[tid];
    float m2 = ws[OFF_M2 + tid];
    float S = 0.f, Ax = 0.f, Ay = 0.f, Az = 0.f, gd2 = 0.f, gl = 0.f;
    #pragma unroll 4
    for (int n = 0; n < NT; ++n) {
        float4 xt = XT[n];
        float T2n = T2s[n];
        float dot = fmaf(xt.x, p.x, fmaf(xt.y, p.y, xt.z * p.z));
        float u = fmaf(twok, dot, p.w);
        float l2 = u - T2n;                 // lgamma in log2 units, <= 0
        float g = exp2f(l2);
        S += g;
        Ax = fmaf(g, xt.x, Ax);
        Ay = fmaf(g, xt.y, Ay);
        Az = fmaf(g, xt.z, Az);
        float d2 = fmaf(-2.0f, dot, xt.w + m2);
        gd2 = fmaf(g, d2, gd2);
        gl  = fmaf(g, l2, gl);
    }
    atomicAdd(ws + OFF_S  + tid, S);
    atomicAdd(ws + OFF_AX + tid, Ax);
    atomicAdd(ws + OFF_AY + tid, Ay);
    atomicAdd(ws + OFF_AZ + tid, Az);

    // block-reduce the two scalars
    const int lane = tid & 63, wid = tid >> 6;
    #pragma unroll
    for (int off = 32; off > 0; off >>= 1) { gd2 += __shfl_xor(gd2, off); gl += __shfl_xor(gl, off); }
    if (lane == 0) { redA[wid] = gd2; redB[wid] = gl; }
    __syncthreads();
    if (tid == 0) {
        atomicAdd(ws + OFF_CONST + 2, redA[0] + redA[1] + redA[2] + redA[3]);
        atomicAdd(ws + OFF_CONST + 3, redB[0] + redB[1] + redB[2] + redB[3]);
    }
}

__global__ __launch_bounds__(256) void gmm_pass2(float* __restrict__ ws, int N)
{
    __shared__ float redA[4], redB[4], redC[4];
    const int c = threadIdx.x;
    const int lane = c & 63, wid = c >> 6;
    float S  = ws[OFF_S  + c];
    float Ax = ws[OFF_AX + c];
    float Ay = ws[OFF_AY + c];
    float Az = ws[OFF_AZ + c];
    float inv = 1.0f / S;
    float mx = Ax * inv, my = Ay * inv, mz = Az * inv;
    ((float4*)(ws + OFF_Q))[c] = make_float4(mx, my, mz, 0.0f);
    float M2 = mx*mx + my*my + mz*mz;
    float a = S, b = S * M2, d = S * logf(S);
    #pragma unroll
    for (int off = 32; off > 0; off >>= 1) { a += __shfl_xor(a, off); b += __shfl_xor(b, off); d += __shfl_xor(d, off); }
    if (lane == 0) { redA[wid] = a; redB[wid] = b; redC[wid] = d; }
    __syncthreads();
    if (c == 0) {
        float sumS     = redA[0] + redA[1] + redA[2] + redA[3];
        float sumSM2   = redB[0] + redB[1] + redB[2] + redB[3];
        float sumSlogS = redC[0] + redC[1] + redC[2] + redC[3];
        float sumSlpi  = sumSlogS - sumS * logf(sumS);
        float sumGD2   = ws[OFF_CONST + 2];
        float sn2      = sumGD2 / (3.0f * (float)N);
        ws[OFF_CONST + 5] = sumSM2;
        ws[OFF_CONST + 6] = sumSlpi;
        ws[OFF_CONST + 7] = 1.0f / (2.0f * sn2);
    }
}

__global__ __launch_bounds__(256) void gmm_pass3(const float* __restrict__ X,
                                                 float* __restrict__ ws,
                                                 float* __restrict__ Yout, int N)
{
    __shared__ float4 P[CC];
    __shared__ float4 Q[CC];
    __shared__ float  redA[4];
    const int tid = threadIdx.x;
    const int n0  = blockIdx.x * TILE;
    const int NT  = min(TILE, N - n0);
    P[tid] = ((const float4*)(ws + OFF_P))[tid];
    Q[tid] = ((const float4*)(ws + OFF_Q))[tid];
    const float twok = ws[OFF_CONST + 0];
    __syncthreads();

    float Y2 = 0.0f;
    if (tid < NT) {
        const int n = n0 + tid;
        float x = X[3*n+0], y = X[3*n+1], z = X[3*n+2];
        float T2 = ws[OFF_T2 + n];
        float Yx = 0.f, Yy = 0.f, Yz = 0.f;
        #pragma unroll 8
        for (int c = 0; c < CC; ++c) {
            float4 p = P[c];
            float dot = fmaf(x, p.x, fmaf(y, p.y, z * p.z));
            float g = exp2f(fmaf(twok, dot, p.w) - T2);
            float4 q = Q[c];
            Yx = fmaf(g, q.x, Yx);
            Yy = fmaf(g, q.y, Yy);
            Yz = fmaf(g, q.z, Yz);
        }
        Yout[3*n+0] = Yx;
        Yout[3*n+1] = Yy;
        Yout[3*n+2] = Yz;
        Y2 = Yx*Yx + Yy*Yy + Yz*Yz;
    }
    const int lane = tid & 63, wid = tid >> 6;
    #pragma unroll
    for (int off = 32; off > 0; off >>= 1) Y2 += __shfl_xor(Y2, off);
    if (lane == 0) redA[wid] = Y2;
    __syncthreads();
    if (tid == 0) atomicAdd(ws + OFF_CONST + 4, redA[0] + redA[1] + redA[2] + redA[3]);
}

__global__ void gmm_pass4(float* __restrict__ ws, float* __restrict__ cfe_out, int N)
{
    if (threadIdx.x == 0) {
        const float ln2 = 0.69314718055994531f;
        float sumSM2  = ws[OFF_CONST + 5];
        float sumSlpi = ws[OFF_CONST + 6];
        float inv2sn2 = ws[OFF_CONST + 7];
        float sumY2   = ws[OFF_CONST + 4];
        float sumGL2  = ws[OFF_CONST + 3];
        float lgn     = ws[OFF_CONST + 1];
        float Cfe = (sumSM2 - sumY2) * inv2sn2 + (float)N * lgn + ln2 * sumGL2 - sumSlpi;
        cfe_out[0] = Cfe;
    }
}

extern "C" void kernel_launch(void* const* d_in, const int* in_sizes, int n_in,
                              void* d_out, int out_size, void* d_ws, size_t ws_size,
                              hipStream_t stream)
{
    const float* X     = (const float*)d_in[0];
    const float* mu    = (const float*)d_in[1];
    const float* w     = (const float*)d_in[2];
    const float* sigma = (const float*)d_in[3];
    float* out = (float*)d_out;
    float* ws  = (float*)d_ws;
    const int N = in_sizes[0] / 3;
    const int nblk = (N + TILE - 1) / TILE;

    // zero accumulators (S, A*, CONST block) — must be per-launch (idempotent)
    hipMemsetAsync((char*)d_ws + OFF_S * sizeof(float), 0,
                   (OFF_T2 - OFF_S) * sizeof(float), stream);

    gmm_prep <<<1,    256, 0, stream>>>(mu, w, sigma, ws);
    gmm_pass1<<<nblk, 256, 0, stream>>>(X, ws, N);
    gmm_pass2<<<1,    256, 0, stream>>>(ws, N);
    gmm_pass3<<<nblk, 256, 0, stream>>>(X, ws, out, N);
    gmm_pass4<<<1,    64,  0, stream>>>(ws, out + (size_t)3 * N, N);
}